// Round 4
// baseline (243.619 us; speedup 1.0000x reference)
//
#include <hip/hip_runtime.h>
#include <math.h>

#define N_MARGIN 0.3f
// Gram GEMM geometry: 128x128 C-tile, BK=64 bf16, 256 threads = 4 waves (2x2),
// each wave 64x64 = 4x4 fragments of mfma_f32_16x16x32_bf16.
// Upper-triangular tiles only (symmetry); double-buffered LDS (T3-minimum);
// XCD-chunked block swizzle (T1).
#define BM 128
#define BK 64

typedef __attribute__((ext_vector_type(8))) short bf16x8;
typedef __attribute__((ext_vector_type(4))) float f32x4;
typedef __attribute__((address_space(3))) unsigned int lds_uint;
typedef __attribute__((address_space(1))) unsigned int gbl_uint;

// float -> bf16 RNE
static __device__ inline unsigned short f2bf(float f) {
    unsigned int u = __builtin_bit_cast(unsigned int, f);
    u = (u + 0x7fffu + ((u >> 16) & 1u)) >> 16;
    return (unsigned short)u;
}

// ---------------------------------------------------------------------------
// Kernel 1: per-row L2-normalize + bf16 convert. One WAVE per row (no block
// syncs); pass 2 re-reads the row from L1.
// ---------------------------------------------------------------------------
__global__ __launch_bounds__(256)
void norm_cvt_k(const float* __restrict__ X, unsigned short* __restrict__ Xb,
                float* __restrict__ rowsq, int d) {
    const int lane = threadIdx.x & 63;
    const int row = blockIdx.x * 4 + (threadIdx.x >> 6);
    const float* xr = X + (size_t)row * d;

    float ss = 0.f;
    for (int k = lane * 4; k < d; k += 256) {
        float4 v = *reinterpret_cast<const float4*>(xr + k);
        ss += v.x * v.x + v.y * v.y + v.z * v.z + v.w * v.w;
    }
#pragma unroll
    for (int m = 32; m > 0; m >>= 1) ss += __shfl_xor(ss, m);  // all lanes get total
    float nrm = sqrtf(ss);
    float inv = 1.f / (nrm + 1e-12f);
    if (lane == 0) {
        float s = nrm * inv;
        rowsq[row] = s * s;
    }
    unsigned short* xb = Xb + (size_t)row * d;
    for (int k = lane * 4; k < d; k += 256) {
        float4 v = *reinterpret_cast<const float4*>(xr + k);  // L1 hit
        uint2 o;
        o.x = (unsigned)f2bf(v.x * inv) | ((unsigned)f2bf(v.y * inv) << 16);
        o.y = (unsigned)f2bf(v.z * inv) | ((unsigned)f2bf(v.w * inv) << 16);
        *reinterpret_cast<uint2*>(xb + k) = o;
    }
}

// ---------------------------------------------------------------------------
// Kernel 2: bf16 MFMA Gram tile (upper-tri) + fused masked-softmax stats,
// double-buffered LDS: STAGE(t+1) issued BEFORE compute(t); one barrier/iter
// (its implicit vmcnt(0)+lgkmcnt(0) drain is exactly the cross-wave handoff).
// LDS swizzle per rule #21: linear global_load_lds dest + inverse-swizzled
// global source + swizzled ds_read.
// ---------------------------------------------------------------------------
__global__ __launch_bounds__(256)
void gram_stats_k(const unsigned short* __restrict__ Xb, const int* __restrict__ tgt,
                  const float* __restrict__ rowsq, float* __restrict__ stats,
                  int n, int d, int nblocks) {
    __shared__ alignas(16) unsigned short As[2][BM * BK];
    __shared__ alignas(16) unsigned short Bs[2][BM * BK];
    __shared__ int   s_ti[BM], s_tj[BM];
    __shared__ float s_qi[BM], s_qj[BM];

    const int tid = threadIdx.x;
    const int lane = tid & 63;
    const int w = tid >> 6;          // wave 0..3
    const int wr = w >> 1, wc = w & 1;

    // T1: XCD-chunked bijective swizzle (nblocks % 8 == 0 here: 528 = 8*66)
    const int cpx = nblocks >> 3;
    const int swz = (blockIdx.x & 7) * cpx + (blockIdx.x >> 3);

    const int nbx = n / BM;          // 32
    int by = 0, rem = swz;
    while (rem >= nbx - by) { rem -= nbx - by; ++by; }
    const int bx = by + rem;
    const bool offdiag = (by != bx);
    const int row0 = by * BM, col0 = bx * BM;

    if (tid < BM) {
        s_ti[tid] = tgt[row0 + tid];
        s_qi[tid] = rowsq[row0 + tid];
    } else {
        int t2 = tid - BM;
        s_tj[t2] = tgt[col0 + t2];
        s_qj[t2] = rowsq[col0 + t2];
    }

    f32x4 acc[4][4];
#pragma unroll
    for (int a = 0; a < 4; ++a)
#pragma unroll
        for (int b = 0; b < 4; ++b) acc[a][b] = (f32x4){0.f, 0.f, 0.f, 0.f};

    // staging lane map: instruction i covers LDS rows 8i..8i+7 (1024 B);
    // lane l -> row 8i + (l>>3), physical slot l&7, global chunk (l&7)^(l>>3)
    const int st_r = lane >> 3;
    const int st_s = (lane & 7) ^ st_r;
    const int rd_x = lane & 7;
    const int rd_k = lane >> 4;

    // stage one K-tile into buffer `buf`
    auto STAGE = [&](int buf, int k0) {
#pragma unroll
        for (int q = 0; q < 4; ++q) {
            int i = 4 * w + q;
            const unsigned short* ga =
                Xb + (size_t)(row0 + 8 * i + st_r) * d + k0 + st_s * 8;
            __builtin_amdgcn_global_load_lds((const gbl_uint*)ga,
                                             (lds_uint*)(&As[buf][i * 512]), 16, 0, 0);
            const unsigned short* gb =
                Xb + (size_t)(col0 + 8 * i + st_r) * d + k0 + st_s * 8;
            __builtin_amdgcn_global_load_lds((const gbl_uint*)gb,
                                             (lds_uint*)(&Bs[buf][i * 512]), 16, 0, 0);
        }
    };

    const int nt = d / BK;
    STAGE(0, 0);
    __syncthreads();

    for (int t = 0; t < nt; ++t) {
        const int cur = t & 1;
        if (t + 1 < nt) STAGE(cur ^ 1, (t + 1) * BK);   // prefetch next tile

#pragma unroll
        for (int ks = 0; ks < 2; ++ks) {
            const int slot = (ks * 4 + rd_k) ^ rd_x;
            bf16x8 af[4], bf[4];
#pragma unroll
            for (int fr = 0; fr < 4; ++fr) {
                int rA = wr * 64 + fr * 16 + (lane & 15);
                af[fr] = *reinterpret_cast<const bf16x8*>(&As[cur][rA * 64 + slot * 8]);
                int rB = wc * 64 + fr * 16 + (lane & 15);
                bf[fr] = *reinterpret_cast<const bf16x8*>(&Bs[cur][rB * 64 + slot * 8]);
            }
#pragma unroll
            for (int fr = 0; fr < 4; ++fr)
#pragma unroll
                for (int nc = 0; nc < 4; ++nc)
                    acc[fr][nc] = __builtin_amdgcn_mfma_f32_16x16x32_bf16(
                        af[fr], bf[nc], acc[fr][nc], 0, 0, 0);
        }
        __syncthreads();   // implicit vmcnt(0)+lgkmcnt(0): prefetch landed, reads done
    }

    // ------------------------------------------------------------------
    // Epilogue. C[row][col]: col = lane&15 (+nc*16 +wc*64),
    //                        row = (lane>>4)*4 + j (+fr*16 +wr*64).
    // Row stats: in-thread nc + shfl_xor {1,2,4,8}.
    // Col stats (off-diag mirror): in-thread (fr,j) + shfl_xor {16,32}.
    // ------------------------------------------------------------------
    int tjv[4]; float qjv[4];
#pragma unroll
    for (int nc = 0; nc < 4; ++nc) {
        int cloc = wc * 64 + nc * 16 + (lane & 15);
        tjv[nc] = s_tj[cloc];
        qjv[nc] = s_qj[cloc];
    }
    float cs0[4], cs1[4], cs2[4], cs3[4];
#pragma unroll
    for (int nc = 0; nc < 4; ++nc) { cs0[nc] = 0.f; cs1[nc] = 0.f; cs2[nc] = 0.f; cs3[nc] = 0.f; }

#pragma unroll
    for (int fr = 0; fr < 4; ++fr) {
#pragma unroll
        for (int j = 0; j < 4; ++j) {
            int rloc = wr * 64 + fr * 16 + (lane >> 4) * 4 + j;
            int grow = row0 + rloc;
            int ti = s_ti[rloc];
            float sqi = s_qi[rloc];
            float pd = 0.f, pn = 0.f, nd = 0.f, nn = 0.f;
#pragma unroll
            for (int nc = 0; nc < 4; ++nc) {
                int gcol = col0 + wc * 64 + nc * 16 + (lane & 15);
                float g = acc[fr][nc][j];
                float d2 = sqi + qjv[nc] - 2.f * g;
                float dist = sqrtf(fmaxf(d2, 1e-12f));
                if (ti == tjv[nc]) {
                    if (grow != gcol) {
                        float e = __expf(dist);
                        pd += e; pn += e * dist;
                        cs0[nc] += e; cs1[nc] += e * dist;
                    }
                } else {
                    float e = __expf(-dist);
                    nd += e; nn += e * dist;
                    cs2[nc] += e; cs3[nc] += e * dist;
                }
            }
            for (int m = 1; m < 16; m <<= 1) {
                pd += __shfl_xor(pd, m);
                pn += __shfl_xor(pn, m);
                nd += __shfl_xor(nd, m);
                nn += __shfl_xor(nn, m);
            }
            if ((lane & 15) == 0) {
                atomicAdd(&stats[grow * 4 + 0], pd);
                atomicAdd(&stats[grow * 4 + 1], pn);
                atomicAdd(&stats[grow * 4 + 2], nd);
                atomicAdd(&stats[grow * 4 + 3], nn);
            }
        }
    }

    if (offdiag) {
#pragma unroll
        for (int nc = 0; nc < 4; ++nc) {
            float a = cs0[nc], b = cs1[nc], c = cs2[nc], e = cs3[nc];
            for (int m = 16; m < 64; m <<= 1) {
                a += __shfl_xor(a, m);
                b += __shfl_xor(b, m);
                c += __shfl_xor(c, m);
                e += __shfl_xor(e, m);
            }
            if (lane < 16) {
                int gcol = col0 + wc * 64 + nc * 16 + lane;
                atomicAdd(&stats[gcol * 4 + 0], a);
                atomicAdd(&stats[gcol * 4 + 1], b);
                atomicAdd(&stats[gcol * 4 + 2], c);
                atomicAdd(&stats[gcol * 4 + 3], e);
            }
        }
    }
}

// ---------------------------------------------------------------------------
// Kernel 3: finalize — loss = mean(relu(pos + MARGIN - neg))
// ---------------------------------------------------------------------------
__global__ void finalize_k(const float* __restrict__ stats, float* __restrict__ out, int n) {
    float s = 0.f;
    for (int i = threadIdx.x; i < n; i += blockDim.x) {
        float4 st = *reinterpret_cast<const float4*>(&stats[i * 4]);
        float v = st.y / st.x + N_MARGIN - st.w / st.z;
        s += fmaxf(v, 0.f);
    }
    for (int m = 32; m > 0; m >>= 1) s += __shfl_down(s, m);
    __shared__ float sp[4];
    int lane = threadIdx.x & 63, wv = threadIdx.x >> 6;
    if (lane == 0) sp[wv] = s;
    __syncthreads();
    if (threadIdx.x == 0) out[0] = (sp[0] + sp[1] + sp[2] + sp[3]) / (float)n;
}

extern "C" void kernel_launch(void* const* d_in, const int* in_sizes, int n_in,
                              void* d_out, int out_size, void* d_ws, size_t ws_size,
                              hipStream_t stream) {
    const float* X = (const float*)d_in[0];
    const int* tgt = (const int*)d_in[1];
    const int n = in_sizes[1];             // 4096
    const int d = in_sizes[0] / n;         // 2048

    unsigned short* Xb = (unsigned short*)d_ws;          // n*d bf16 (16 MB)
    float* rowsq = (float*)(Xb + (size_t)n * d);         // n floats
    float* stats = rowsq + n;                            // 4n floats

    hipMemsetAsync(stats, 0, (size_t)n * 4 * sizeof(float), stream);
    norm_cvt_k<<<n / 4, 256, 0, stream>>>(X, Xb, rowsq, d);
    const int nbx = n / BM;                              // 32
    const int nblocks = nbx * (nbx + 1) / 2;             // 528 upper-tri tiles
    gram_stats_k<<<nblocks, 256, 0, stream>>>(Xb, tgt, rowsq, stats, n, d, nblocks);
    finalize_k<<<1, 256, 0, stream>>>(stats, (float*)d_out, n);
}

// Round 5
// 208.911 us; speedup vs baseline: 1.1661x; 1.1661x over previous
//
#include <hip/hip_runtime.h>
#include <math.h>

#define N_MARGIN 0.3f
// Gram GEMM: 128x128 C-tile, BK=32 bf16 double-buffered (LDS 34.3KB -> 4
// blocks/CU so the 528-tile upper-tri grid fits ONE scheduling round).
// 256 threads = 4 waves (2x2), each wave 64x64 = 4x4 frags of 16x16x32 bf16.
// Super-tile (4x4 tiles) serpentine order + XCD chunking for L2 panel reuse.
#define BM 128
#define BK 32

typedef __attribute__((ext_vector_type(8))) short bf16x8;
typedef __attribute__((ext_vector_type(4))) float f32x4;
typedef __attribute__((address_space(3))) unsigned int lds_uint;
typedef __attribute__((address_space(1))) unsigned int gbl_uint;

// float -> bf16 RNE
static __device__ inline unsigned short f2bf(float f) {
    unsigned int u = __builtin_bit_cast(unsigned int, f);
    u = (u + 0x7fffu + ((u >> 16) & 1u)) >> 16;
    return (unsigned short)u;
}

// ---------------------------------------------------------------------------
// Kernel 1: per-row L2-normalize + bf16 convert. One wave per row.
// ---------------------------------------------------------------------------
__global__ __launch_bounds__(256)
void norm_cvt_k(const float* __restrict__ X, unsigned short* __restrict__ Xb,
                float* __restrict__ rowsq, int d) {
    const int lane = threadIdx.x & 63;
    const int row = blockIdx.x * 4 + (threadIdx.x >> 6);
    const float* xr = X + (size_t)row * d;

    float ss = 0.f;
    for (int k = lane * 4; k < d; k += 256) {
        float4 v = *reinterpret_cast<const float4*>(xr + k);
        ss += v.x * v.x + v.y * v.y + v.z * v.z + v.w * v.w;
    }
#pragma unroll
    for (int m = 32; m > 0; m >>= 1) ss += __shfl_xor(ss, m);
    float nrm = sqrtf(ss);
    float inv = 1.f / (nrm + 1e-12f);
    if (lane == 0) {
        float s = nrm * inv;
        rowsq[row] = s * s;
    }
    unsigned short* xb = Xb + (size_t)row * d;
    for (int k = lane * 4; k < d; k += 256) {
        float4 v = *reinterpret_cast<const float4*>(xr + k);  // L1 hit
        uint2 o;
        o.x = (unsigned)f2bf(v.x * inv) | ((unsigned)f2bf(v.y * inv) << 16);
        o.y = (unsigned)f2bf(v.z * inv) | ((unsigned)f2bf(v.w * inv) << 16);
        *reinterpret_cast<uint2*>(xb + k) = o;
    }
}

// ---------------------------------------------------------------------------
// Kernel 2: bf16 MFMA Gram (upper-tri tiles) + fused masked-softmax stats.
// BK=32 dbuf; swizzle: tile chunk s of LDS row r lives at phys slot s^(r&3)
// (linear global_load_lds dest + inverse-swizzled global source + swizzled
// ds_read — both-sides rule). A wave's frag read touches 64 distinct 16B
// chunks -> conflict-free.
// ---------------------------------------------------------------------------
__global__ __launch_bounds__(256, 4)
void gram_stats_k(const unsigned short* __restrict__ Xb, const int* __restrict__ tgt,
                  const float* __restrict__ rowsq, float* __restrict__ stats,
                  int n, int d, int nblocks) {
    __shared__ alignas(16) unsigned short As[2][BM * BK];   // 8KB each buf
    __shared__ alignas(16) unsigned short Bs[2][BM * BK];
    __shared__ int   s_ti[BM], s_tj[BM];
    __shared__ float s_qi[BM], s_qj[BM];

    const int tid = threadIdx.x;
    const int lane = tid & 63;
    const int w = tid >> 6;          // wave 0..3
    const int wr = w >> 1, wc = w & 1;

    // XCD chunking over the super-tile serpentine order (528 = 8 * 66)
    const int cpx = nblocks >> 3;
    int rem = (blockIdx.x & 7) * cpx + (blockIdx.x >> 3);

    // decode rem -> (by,bx) via serpentine 4x4 super-tiles over the 8x8
    // upper-tri super-grid. diag super = 10 tiles, off-diag = 16.
    int BY = -1, BX = -1;
    for (int y = 0; y < 8 && BY < 0; ++y) {
        for (int t = 0; t < 8 - y; ++t) {
            int x = (y & 1) ? (7 - t) : (y + t);
            int c = (x == y) ? 10 : 16;
            if (rem < c) { BY = y; BX = x; break; }
            rem -= c;
        }
    }
    int dy, dx;
    if (BX == BY) {                      // 10 pairs dy<=dx
        dy = 0;
        while (rem >= 4 - dy) { rem -= 4 - dy; ++dy; }
        dx = dy + rem;
    } else { dy = rem >> 2; dx = rem & 3; }
    const int by = BY * 4 + dy, bx = BX * 4 + dx;
    const bool offdiag = (by != bx);
    const int row0 = by * BM, col0 = bx * BM;

    if (tid < BM) {
        s_ti[tid] = tgt[row0 + tid];
        s_qi[tid] = rowsq[row0 + tid];
    } else {
        int t2 = tid - BM;
        s_tj[t2] = tgt[col0 + t2];
        s_qj[t2] = rowsq[col0 + t2];
    }

    f32x4 acc[4][4];
#pragma unroll
    for (int a = 0; a < 4; ++a)
#pragma unroll
        for (int b = 0; b < 4; ++b) acc[a][b] = (f32x4){0.f, 0.f, 0.f, 0.f};

    // staging map: instruction i covers LDS rows 16i..16i+15 (1KB);
    // lane l -> row 16i+(l>>2), phys slot l&3, global chunk (l&3)^((l>>2)&3)
    const int st_r = lane >> 2;
    const int st_s = (lane & 3) ^ ((lane >> 2) & 3);
    // read swizzle: phys chunk = (lane>>4) ^ (rowA&3), rowA&3 == lane&3
    const int rd_p = (lane >> 4) ^ (lane & 3);

    auto STAGE = [&](int buf, int k0) {
#pragma unroll
        for (int q = 0; q < 2; ++q) {
            int i = 2 * w + q;
            const unsigned short* ga =
                Xb + (size_t)(row0 + 16 * i + st_r) * d + k0 + st_s * 8;
            __builtin_amdgcn_global_load_lds((const gbl_uint*)ga,
                                             (lds_uint*)(&As[buf][i * 512]), 16, 0, 0);
            const unsigned short* gb =
                Xb + (size_t)(col0 + 16 * i + st_r) * d + k0 + st_s * 8;
            __builtin_amdgcn_global_load_lds((const gbl_uint*)gb,
                                             (lds_uint*)(&Bs[buf][i * 512]), 16, 0, 0);
        }
    };

    const int nt = d / BK;              // 64
    STAGE(0, 0);
    __syncthreads();

    for (int t = 0; t < nt; ++t) {
        const int cur = t & 1;
        if (t + 1 < nt) STAGE(cur ^ 1, (t + 1) * BK);   // prefetch next tile

        bf16x8 af[4], bfr[4];
#pragma unroll
        for (int fr = 0; fr < 4; ++fr) {
            int rA = wr * 64 + fr * 16 + (lane & 15);
            af[fr] = *reinterpret_cast<const bf16x8*>(&As[cur][rA * 32 + rd_p * 8]);
            int rB = wc * 64 + fr * 16 + (lane & 15);
            bfr[fr] = *reinterpret_cast<const bf16x8*>(&Bs[cur][rB * 32 + rd_p * 8]);
        }
#pragma unroll
        for (int fr = 0; fr < 4; ++fr)
#pragma unroll
            for (int nc = 0; nc < 4; ++nc)
                acc[fr][nc] = __builtin_amdgcn_mfma_f32_16x16x32_bf16(
                    af[fr], bfr[nc], acc[fr][nc], 0, 0, 0);

        __syncthreads();   // implicit vmcnt(0)+lgkmcnt(0): prefetch landed, reads done
    }

    // ------------------------------------------------------------------
    // Epilogue. C[row][col]: col = lane&15 (+nc*16 +wc*64),
    //                        row = (lane>>4)*4 + j (+fr*16 +wr*64).
    // Row stats: in-thread nc + shfl_xor {1,2,4,8}.
    // Col stats (off-diag mirror): in-thread (fr,j) + shfl_xor {16,32}.
    // ------------------------------------------------------------------
    int tjv[4]; float qjv[4];
#pragma unroll
    for (int nc = 0; nc < 4; ++nc) {
        int cloc = wc * 64 + nc * 16 + (lane & 15);
        tjv[nc] = s_tj[cloc];
        qjv[nc] = s_qj[cloc];
    }
    float cs0[4], cs1[4], cs2[4], cs3[4];
#pragma unroll
    for (int nc = 0; nc < 4; ++nc) { cs0[nc] = 0.f; cs1[nc] = 0.f; cs2[nc] = 0.f; cs3[nc] = 0.f; }

#pragma unroll
    for (int fr = 0; fr < 4; ++fr) {
#pragma unroll
        for (int j = 0; j < 4; ++j) {
            int rloc = wr * 64 + fr * 16 + (lane >> 4) * 4 + j;
            int grow = row0 + rloc;
            int ti = s_ti[rloc];
            float sqi = s_qi[rloc];
            float pd = 0.f, pn = 0.f, nd = 0.f, nn = 0.f;
#pragma unroll
            for (int nc = 0; nc < 4; ++nc) {
                int gcol = col0 + wc * 64 + nc * 16 + (lane & 15);
                float g = acc[fr][nc][j];
                float d2 = sqi + qjv[nc] - 2.f * g;
                float dist = sqrtf(fmaxf(d2, 1e-12f));
                if (ti == tjv[nc]) {
                    if (grow != gcol) {
                        float e = __expf(dist);
                        pd += e; pn += e * dist;
                        cs0[nc] += e; cs1[nc] += e * dist;
                    }
                } else {
                    float e = __expf(-dist);
                    nd += e; nn += e * dist;
                    cs2[nc] += e; cs3[nc] += e * dist;
                }
            }
            for (int m = 1; m < 16; m <<= 1) {
                pd += __shfl_xor(pd, m);
                pn += __shfl_xor(pn, m);
                nd += __shfl_xor(nd, m);
                nn += __shfl_xor(nn, m);
            }
            if ((lane & 15) == 0) {
                atomicAdd(&stats[grow * 4 + 0], pd);
                atomicAdd(&stats[grow * 4 + 1], pn);
                atomicAdd(&stats[grow * 4 + 2], nd);
                atomicAdd(&stats[grow * 4 + 3], nn);
            }
        }
    }

    if (offdiag) {
#pragma unroll
        for (int nc = 0; nc < 4; ++nc) {
            float a = cs0[nc], b = cs1[nc], c = cs2[nc], e = cs3[nc];
            for (int m = 16; m < 64; m <<= 1) {
                a += __shfl_xor(a, m);
                b += __shfl_xor(b, m);
                c += __shfl_xor(c, m);
                e += __shfl_xor(e, m);
            }
            if (lane < 16) {
                int gcol = col0 + wc * 64 + nc * 16 + lane;
                atomicAdd(&stats[gcol * 4 + 0], a);
                atomicAdd(&stats[gcol * 4 + 1], b);
                atomicAdd(&stats[gcol * 4 + 2], c);
                atomicAdd(&stats[gcol * 4 + 3], e);
            }
        }
    }
}

// ---------------------------------------------------------------------------
// Kernel 3: finalize — loss = mean(relu(pos + MARGIN - neg))
// ---------------------------------------------------------------------------
__global__ void finalize_k(const float* __restrict__ stats, float* __restrict__ out, int n) {
    float s = 0.f;
    for (int i = threadIdx.x; i < n; i += blockDim.x) {
        float4 st = *reinterpret_cast<const float4*>(&stats[i * 4]);
        float v = st.y / st.x + N_MARGIN - st.w / st.z;
        s += fmaxf(v, 0.f);
    }
    for (int m = 32; m > 0; m >>= 1) s += __shfl_down(s, m);
    __shared__ float sp[4];
    int lane = threadIdx.x & 63, wv = threadIdx.x >> 6;
    if (lane == 0) sp[wv] = s;
    __syncthreads();
    if (threadIdx.x == 0) out[0] = (sp[0] + sp[1] + sp[2] + sp[3]) / (float)n;
}

extern "C" void kernel_launch(void* const* d_in, const int* in_sizes, int n_in,
                              void* d_out, int out_size, void* d_ws, size_t ws_size,
                              hipStream_t stream) {
    const float* X = (const float*)d_in[0];
    const int* tgt = (const int*)d_in[1];
    const int n = in_sizes[1];             // 4096
    const int d = in_sizes[0] / n;         // 2048

    unsigned short* Xb = (unsigned short*)d_ws;          // n*d bf16 (16 MB)
    float* rowsq = (float*)(Xb + (size_t)n * d);         // n floats
    float* stats = rowsq + n;                            // 4n floats

    hipMemsetAsync(stats, 0, (size_t)n * 4 * sizeof(float), stream);
    norm_cvt_k<<<n / 4, 256, 0, stream>>>(X, Xb, rowsq, d);
    const int nbx = n / BM;                              // 32
    const int nblocks = nbx * (nbx + 1) / 2;             // 528 upper-tri tiles
    gram_stats_k<<<nblocks, 256, 0, stream>>>(Xb, tgt, rowsq, stats, n, d, nblocks);
    finalize_k<<<1, 256, 0, stream>>>(stats, (float*)d_out, n);
}